// Round 1
// baseline (189.183 us; speedup 1.0000x reference)
//
#include <hip/hip_runtime.h>
#include <hip/hip_bf16.h>
#include <cstdint>
#include <cstddef>

#define N_ROWS 8192
#define K_DIM  256
#define NP     5532
#define NQ     5000
#define NC     10532
#define IGN    5554
#define BM     128
#define BN     128
#define BK     64
#define CT     83      // ceil(10532/128)
#define CT2    166     // CT * 2 wave-columns

using f32x4  = __attribute__((ext_vector_type(4))) float;
using bf16x8 = __attribute__((ext_vector_type(8))) short;

__device__ __forceinline__ unsigned short f2bf(float f) {
    __hip_bfloat16 h = __float2bfloat16(f);
    return __builtin_bit_cast(unsigned short, h);
}

// GEMM tile + fused exp-sum / label-logit epilogue.
// Grid: (CT, N_ROWS/BM), block 256 (4 waves as 2x2 of 64x64 output each).
__global__ __launch_bounds__(256) void oim_gemm(
    const float* __restrict__ X, const int* __restrict__ roi,
    const float* __restrict__ lut, const float* __restrict__ cq,
    float* __restrict__ partial, float* __restrict__ labelLogit)
{
    const int ct   = blockIdx.x;
    const int rt   = blockIdx.y;
    const int row0 = rt * BM;
    const int col0 = ct * BN;
    const int tid  = threadIdx.x;
    const int wave = tid >> 6;
    const int lane = tid & 63;
    const int wm   = (wave >> 1) * 64;   // wave row offset
    const int wn   = (wave & 1) * 64;    // wave col offset

    __shared__ __align__(16) unsigned short As[BM * BK];
    __shared__ __align__(16) unsigned short Bs[BN * BK];
    __shared__ int lbl[BM];

    if (tid < BM) lbl[tid] = roi[row0 + tid] - 1;

    f32x4 acc[4][4] = {};

    for (int k0 = 0; k0 < K_DIM; k0 += BK) {
        __syncthreads();
        // ---- stage A: 128 rows x 64 k, f32 -> bf16, XOR-swizzled LDS ----
#pragma unroll
        for (int i = 0; i < 8; ++i) {
            int f  = i * 256 + tid;          // float4 index in [0,2048)
            int r  = f >> 4;                 // 16 float4 per row
            int k4 = f & 15;
            float4 v = *reinterpret_cast<const float4*>(
                X + (size_t)(row0 + r) * K_DIM + k0 + k4 * 4);
            ushort4 h;
            h.x = f2bf(v.x); h.y = f2bf(v.y); h.z = f2bf(v.z); h.w = f2bf(v.w);
            int byt = r * 128 + ((k4 * 8) ^ ((r & 7) << 4));
            *reinterpret_cast<ushort4*>(reinterpret_cast<char*>(As) + byt) = h;
        }
        // ---- stage B: 128 classes x 64 k (class-major = B^T layout) ----
#pragma unroll
        for (int i = 0; i < 8; ++i) {
            int f  = i * 256 + tid;
            int c  = f >> 4;
            int k4 = f & 15;
            int gcol = col0 + c;
            if (gcol > NC - 1) gcol = NC - 1;        // clamp tail (masked later)
            const float* src = (gcol < NP) ? (lut + (size_t)gcol * K_DIM)
                                           : (cq  + (size_t)(gcol - NP) * K_DIM);
            float4 v = *reinterpret_cast<const float4*>(src + k0 + k4 * 4);
            ushort4 h;
            h.x = f2bf(v.x); h.y = f2bf(v.y); h.z = f2bf(v.z); h.w = f2bf(v.w);
            int byt = c * 128 + ((k4 * 8) ^ ((c & 7) << 4));
            *reinterpret_cast<ushort4*>(reinterpret_cast<char*>(Bs) + byt) = h;
        }
        __syncthreads();
        // ---- compute: 2 k-steps of 32, 4x4 fragments of 16x16x32 ----
#pragma unroll
        for (int kk = 0; kk < 2; ++kk) {
            bf16x8 av[4], bv[4];
#pragma unroll
            for (int m = 0; m < 4; ++m) {
                int r  = wm + m * 16 + (lane & 15);
                int kb = kk * 64 + ((lane >> 4) * 16);
                av[m] = *reinterpret_cast<bf16x8*>(
                    reinterpret_cast<char*>(As) + r * 128 + (kb ^ ((r & 7) << 4)));
            }
#pragma unroll
            for (int n = 0; n < 4; ++n) {
                int c  = wn + n * 16 + (lane & 15);
                int kb = kk * 64 + ((lane >> 4) * 16);
                bv[n] = *reinterpret_cast<bf16x8*>(
                    reinterpret_cast<char*>(Bs) + c * 128 + (kb ^ ((c & 7) << 4)));
            }
#pragma unroll
            for (int m = 0; m < 4; ++m)
#pragma unroll
                for (int n = 0; n < 4; ++n)
                    acc[m][n] = __builtin_amdgcn_mfma_f32_16x16x32_bf16(
                        av[m], bv[n], acc[m][n], 0, 0, 0);
        }
    }

    // ---- epilogue: logits*30, exp(logit-30) sums per row, label capture ----
    // C frag layout (verified m89): col = lane&15, row = (lane>>4)*4 + reg
#pragma unroll
    for (int m = 0; m < 4; ++m) {
#pragma unroll
        for (int reg = 0; reg < 4; ++reg) {
            int lrow = wm + m * 16 + (lane >> 4) * 4 + reg;
            int grow = row0 + lrow;
            int lab  = lbl[lrow];
            float s = 0.0f;
#pragma unroll
            for (int n = 0; n < 4; ++n) {
                int gcol = col0 + wn + n * 16 + (lane & 15);
                float logit = acc[m][n][reg] * 30.0f;
                if (gcol < NC) {
                    s += __expf(logit - 30.0f);
                    if (gcol == lab) labelLogit[grow] = logit;
                }
            }
#pragma unroll
            for (int off = 1; off < 16; off <<= 1) s += __shfl_xor(s, off, 64);
            if ((lane & 15) == 0)
                partial[(size_t)(ct * 2 + (wn >> 6)) * N_ROWS + grow] = s;
        }
    }
}

// Per-row: sum partials (fixed order -> deterministic), nll + valid flag.
__global__ __launch_bounds__(256) void oim_rownll(
    const float* __restrict__ partial, const float* __restrict__ labelLogit,
    const int* __restrict__ roi, float* __restrict__ nll, float* __restrict__ vld)
{
    int r = blockIdx.x * 256 + threadIdx.x;
    float S = 0.0f;
    for (int t = 0; t < CT2; ++t) S += partial[(size_t)t * N_ROWS + r];
    float lse = 30.0f + logf(S);
    int lab = roi[r] - 1;
    bool valid = (lab != IGN);
    nll[r] = valid ? (lse - labelLogit[r]) : 0.0f;
    vld[r] = valid ? 1.0f : 0.0f;
}

// Single-block deterministic tree reduction to the scalar loss.
__global__ __launch_bounds__(256) void oim_reduce(
    const float* __restrict__ nll, const float* __restrict__ vld,
    float* __restrict__ out)
{
    __shared__ float s1[256], s2[256];
    int tid = threadIdx.x;
    float a = 0.0f, b = 0.0f;
    for (int r = tid; r < N_ROWS; r += 256) { a += nll[r]; b += vld[r]; }
    s1[tid] = a; s2[tid] = b;
    __syncthreads();
    for (int o = 128; o > 0; o >>= 1) {
        if (tid < o) { s1[tid] += s1[tid + o]; s2[tid] += s2[tid + o]; }
        __syncthreads();
    }
    if (tid == 0) out[0] = s1[0] / fmaxf(s2[0], 1.0f);
}

extern "C" void kernel_launch(void* const* d_in, const int* in_sizes, int n_in,
                              void* d_out, int out_size, void* d_ws, size_t ws_size,
                              hipStream_t stream)
{
    const float* X   = (const float*)d_in[0];
    const int*   roi = (const int*)  d_in[1];
    const float* lut = (const float*)d_in[2];
    const float* cq  = (const float*)d_in[3];
    float* out = (float*)d_out;

    char* ws = (char*)d_ws;
    float* partial    = (float*)ws;                               // CT2 * N_ROWS
    float* nll        = (float*)(ws + (size_t)CT2 * N_ROWS * 4);  // N_ROWS
    float* vld        = nll + N_ROWS;                             // N_ROWS
    float* labelLogit = vld + N_ROWS;                             // N_ROWS
    size_t need = (size_t)CT2 * N_ROWS * 4 + (size_t)3 * N_ROWS * 4;
    if (ws_size < need) return;  // refuse to run rather than corrupt memory

    dim3 g1(CT, N_ROWS / BM);
    oim_gemm<<<g1, 256, 0, stream>>>(X, roi, lut, cq, partial, labelLogit);
    oim_rownll<<<N_ROWS / 256, 256, 0, stream>>>(partial, labelLogit, roi, nll, vld);
    oim_reduce<<<1, 256, 0, stream>>>(nll, vld, out);
}

// Round 2
// 117.113 us; speedup vs baseline: 1.6154x; 1.6154x over previous
//
#include <hip/hip_runtime.h>
#include <hip/hip_bf16.h>
#include <cstdint>
#include <cstddef>

#define N_ROWS 8192
#define K_DIM  256
#define NP     5532
#define NC     10532
#define NCPAD  10624    // 83*128, zero-padded classes
#define IGN    5554
#define BM     128
#define BN     128
#define BK     64
#define CT     83       // NCPAD / BN
#define NBLK   (CT * 64)   // 5312 blocks, % 8 == 0 -> simple bijective XCD swizzle
#define CPX    (NBLK / 8)  // 664

using f32x4  = __attribute__((ext_vector_type(4))) float;
using bf16x8 = __attribute__((ext_vector_type(8))) short;

__device__ __forceinline__ unsigned short f2bf(float f) {
    __hip_bfloat16 h = __float2bfloat16(f);
    return __builtin_bit_cast(unsigned short, h);
}

// One-shot f32 -> bf16 conversion of X and W=[lut;cq;zero-pad] into workspace.
__global__ __launch_bounds__(256) void oim_convert(
    const float* __restrict__ X, const float* __restrict__ lut,
    const float* __restrict__ cq,
    unsigned short* __restrict__ Xb, unsigned short* __restrict__ Wb)
{
    const int XCH = (N_ROWS * K_DIM) / 8;   // 262144 chunks of 8 elems
    const int WCH = (NCPAD * K_DIM) / 8;    // 339968
    for (int c = blockIdx.x * 256 + threadIdx.x; c < XCH + WCH;
         c += gridDim.x * 256) {
        const float* src = nullptr;
        unsigned short* dst;
        if (c < XCH) {
            src = X + (size_t)c * 8;
            dst = Xb + (size_t)c * 8;
        } else {
            int wc  = c - XCH;
            int row = wc >> 5;          // 32 chunks per 256-elem row
            int off = (wc & 31) * 8;
            dst = Wb + (size_t)wc * 8;
            if (row < NP)      src = lut + (size_t)row * K_DIM + off;
            else if (row < NC) src = cq + (size_t)(row - NP) * K_DIM + off;
        }
        ushort4 h0 = {0, 0, 0, 0}, h1 = {0, 0, 0, 0};
        if (src) {
            float4 v0 = *reinterpret_cast<const float4*>(src);
            float4 v1 = *reinterpret_cast<const float4*>(src + 4);
            h0.x = f2bf(v0.x); h0.y = f2bf(v0.y); h0.z = f2bf(v0.z); h0.w = f2bf(v0.w);
            h1.x = f2bf(v1.x); h1.y = f2bf(v1.y); h1.z = f2bf(v1.z); h1.w = f2bf(v1.w);
        }
        *reinterpret_cast<ushort4*>(dst)     = h0;
        *reinterpret_cast<ushort4*>(dst + 4) = h1;
    }
}

// 128x128 bf16 GEMM tile (m97 structure: global_load_lds w=16, 2-barrier loop)
// + fused exp-sum / label-logit epilogue. LDS is XOR-swizzled via pre-swizzled
// global source addresses (linear LDS dest as global_load_lds requires).
__global__ __launch_bounds__(256) void oim_gemm(
    const unsigned short* __restrict__ Xb, const unsigned short* __restrict__ Wb,
    const int* __restrict__ roi,
    float* __restrict__ partial, float* __restrict__ labelLogit)
{
    const int bid = blockIdx.x;
    const int L   = (bid & 7) * CPX + (bid >> 3);   // XCD-chunked, bijective
    const int ct  = L >> 6;                          // 0..82  (class tile)
    const int rt  = L & 63;                          // 0..63  (row tile)
    const int row0 = rt * BM;
    const int col0 = ct * BN;
    const int tid  = threadIdx.x;
    const int wave = tid >> 6;
    const int lane = tid & 63;
    const int wm   = (wave >> 1) * 64;
    const int wn   = (wave & 1) * 64;

    __shared__ __align__(16) unsigned short As[BM * BK];
    __shared__ __align__(16) unsigned short Bs[BN * BK];
    __shared__ int   lbl[BM];
    __shared__ float rs[BM][2];

    if (tid < BM) lbl[tid] = roi[row0 + tid] - 1;

    const unsigned short* Asrc = Xb + (size_t)row0 * K_DIM;
    const unsigned short* Bsrc = Wb + (size_t)col0 * K_DIM;

    f32x4 acc[4][4] = {};

    for (int k0 = 0; k0 < K_DIM; k0 += BK) {
        __syncthreads();
        // stage A then B: linear LDS dest (chunk*16B), source pre-swizzled so
        // LDS holds the st-16x32-style XOR layout the reads expect.
#pragma unroll
        for (int i = 0; i < 4; ++i) {
            int chunk = i * 256 + wave * 64 + lane;
            int r = chunk >> 3;                              // row in tile
            int k = ((chunk & 7) * 8) ^ ((r & 7) << 3);      // swizzled k-elem
            __builtin_amdgcn_global_load_lds(
                (const __attribute__((address_space(1))) void*)
                    (Asrc + (size_t)r * K_DIM + k0 + k),
                (__attribute__((address_space(3))) void*)
                    ((char*)As + (size_t)(i * 256 + wave * 64) * 16),
                16, 0, 0);
        }
#pragma unroll
        for (int i = 0; i < 4; ++i) {
            int chunk = i * 256 + wave * 64 + lane;
            int c = chunk >> 3;
            int k = ((chunk & 7) * 8) ^ ((c & 7) << 3);
            __builtin_amdgcn_global_load_lds(
                (const __attribute__((address_space(1))) void*)
                    (Bsrc + (size_t)c * K_DIM + k0 + k),
                (__attribute__((address_space(3))) void*)
                    ((char*)Bs + (size_t)(i * 256 + wave * 64) * 16),
                16, 0, 0);
        }
        __syncthreads();   // compiler emits vmcnt(0) drain + barrier
#pragma unroll
        for (int kk = 0; kk < 2; ++kk) {
            bf16x8 av[4], bv[4];
#pragma unroll
            for (int m = 0; m < 4; ++m) {
                int r  = wm + m * 16 + (lane & 15);
                int kb = kk * 64 + ((lane >> 4) * 16);       // byte offset
                av[m] = *reinterpret_cast<bf16x8*>(
                    reinterpret_cast<char*>(As) + r * 128 + (kb ^ ((r & 7) << 4)));
            }
#pragma unroll
            for (int n = 0; n < 4; ++n) {
                int c  = wn + n * 16 + (lane & 15);
                int kb = kk * 64 + ((lane >> 4) * 16);
                bv[n] = *reinterpret_cast<bf16x8*>(
                    reinterpret_cast<char*>(Bs) + c * 128 + (kb ^ ((c & 7) << 4)));
            }
#pragma unroll
            for (int m = 0; m < 4; ++m)
#pragma unroll
                for (int n = 0; n < 4; ++n)
                    acc[m][n] = __builtin_amdgcn_mfma_f32_16x16x32_bf16(
                        av[m], bv[n], acc[m][n], 0, 0, 0);
        }
    }

    // epilogue: logits*30, exp(logit-30) row-sums, label-logit capture.
    // C frag layout: col = lane&15, row = (lane>>4)*4 + reg (m89-verified).
#pragma unroll
    for (int m = 0; m < 4; ++m) {
#pragma unroll
        for (int reg = 0; reg < 4; ++reg) {
            int lrow = wm + m * 16 + (lane >> 4) * 4 + reg;
            int grow = row0 + lrow;
            int lab  = lbl[lrow];
            float s = 0.0f;
#pragma unroll
            for (int n = 0; n < 4; ++n) {
                int gcol = col0 + wn + n * 16 + (lane & 15);
                float logit = acc[m][n][reg] * 30.0f;
                if (gcol < NC) {                 // masks the zero-pad classes
                    s += __expf(logit - 30.0f);
                    if (gcol == lab) labelLogit[grow] = logit;  // unique writer
                }
            }
#pragma unroll
            for (int off = 1; off < 16; off <<= 1) s += __shfl_xor(s, off, 64);
            if ((lane & 15) == 0) rs[lrow][wave & 1] = s;
        }
    }
    __syncthreads();
    if (tid < BM)
        partial[(size_t)ct * N_ROWS + row0 + tid] = rs[tid][0] + rs[tid][1];
}

// Per-row: fixed-order partial sum (deterministic), nll + valid flag.
__global__ __launch_bounds__(256) void oim_rownll(
    const float* __restrict__ partial, const float* __restrict__ labelLogit,
    const int* __restrict__ roi, float* __restrict__ nll, float* __restrict__ vld)
{
    int r = blockIdx.x * 256 + threadIdx.x;
    float S = 0.0f;
    for (int t = 0; t < CT; ++t) S += partial[(size_t)t * N_ROWS + r];
    float lse = 30.0f + logf(S);
    int lab = roi[r] - 1;
    bool valid = (lab != IGN);
    nll[r] = valid ? (lse - labelLogit[r]) : 0.0f;
    vld[r] = valid ? 1.0f : 0.0f;
}

// Single-block deterministic tree reduction to the scalar loss.
__global__ __launch_bounds__(256) void oim_reduce(
    const float* __restrict__ nll, const float* __restrict__ vld,
    float* __restrict__ out)
{
    __shared__ float s1[256], s2[256];
    int tid = threadIdx.x;
    float a = 0.0f, b = 0.0f;
    for (int r = tid; r < N_ROWS; r += 256) { a += nll[r]; b += vld[r]; }
    s1[tid] = a; s2[tid] = b;
    __syncthreads();
    for (int o = 128; o > 0; o >>= 1) {
        if (tid < o) { s1[tid] += s1[tid + o]; s2[tid] += s2[tid + o]; }
        __syncthreads();
    }
    if (tid == 0) out[0] = s1[0] / fmaxf(s2[0], 1.0f);
}

extern "C" void kernel_launch(void* const* d_in, const int* in_sizes, int n_in,
                              void* d_out, int out_size, void* d_ws, size_t ws_size,
                              hipStream_t stream)
{
    const float* X   = (const float*)d_in[0];
    const int*   roi = (const int*)  d_in[1];
    const float* lut = (const float*)d_in[2];
    const float* cq  = (const float*)d_in[3];
    float* out = (float*)d_out;

    char* ws = (char*)d_ws;
    unsigned short* Xb = (unsigned short*)ws;                 // 8192*256 bf16
    unsigned short* Wb = Xb + (size_t)N_ROWS * K_DIM;         // 10624*256 bf16
    float* partial     = (float*)(Wb + (size_t)NCPAD * K_DIM); // 83*8192 f32
    float* nll         = partial + (size_t)CT * N_ROWS;
    float* vld         = nll + N_ROWS;
    float* labelLogit  = vld + N_ROWS;
    size_t need = (size_t)N_ROWS * K_DIM * 2 + (size_t)NCPAD * K_DIM * 2
                + (size_t)CT * N_ROWS * 4 + (size_t)3 * N_ROWS * 4;
    if (ws_size < need) return;   // refuse to run rather than corrupt memory

    oim_convert<<<2048, 256, 0, stream>>>(X, lut, cq, Xb, Wb);
    oim_gemm<<<NBLK, 256, 0, stream>>>(Xb, Wb, roi, partial, labelLogit);
    oim_rownll<<<N_ROWS / 256, 256, 0, stream>>>(partial, labelLogit, roi, nll, vld);
    oim_reduce<<<1, 256, 0, stream>>>(nll, vld, out);
}